// Round 13
// baseline (325.096 us; speedup 1.0000x reference)
//
#include <hip/hip_runtime.h>
#include <hip/hip_bf16.h>
#include <math.h>

// N=50000, E=800000, C=128, H=4, D=32, G=8 (group size 16).
#define CN 128
#define NBLK 128         // blocks in fused build kernel (co-resident: 128 <= 256 CUs)
#define BSH 8            // bucket = dst >> 8 (256 nodes/bucket); N<2^16 packs in int2

typedef __attribute__((ext_vector_type(8))) short bf16x8;
typedef __attribute__((ext_vector_type(4))) float f32x4;

// fp32 -> bf16 RTNE (bit trick; inputs are finite)
static __device__ inline unsigned int pack_bf16x2(float lo, float hi) {
    unsigned int ul = __float_as_uint(lo);
    unsigned int uh = __float_as_uint(hi);
    ul = (ul + 0x7fffu + ((ul >> 16) & 1u)) >> 16;
    uh = (uh + 0x7fffu + ((uh >> 16) & 1u)) & 0xffff0000u;
    return ul | uh;
}
static __device__ inline unsigned short bf16_of(float v) {
    unsigned int u = __float_as_uint(v);
    return (unsigned short)((u + 0x7fffu + ((u >> 16) & 1u)) >> 16);
}

// Grid barrier: sense-reversing, agent-scope atomics. All NBLK blocks are
// co-resident (128 <= 256 CUs) so spinning is deadlock-free. state memset 0.
static __device__ __forceinline__ void gbar(int* cnt, int* gen, int nb) {
    __syncthreads();
    if (threadIdx.x == 0) {
        __threadfence();    // release: make this block's stores visible
        int g = __hip_atomic_load(gen, __ATOMIC_RELAXED, __HIP_MEMORY_SCOPE_AGENT);
        int a = __hip_atomic_fetch_add(cnt, 1, __ATOMIC_ACQ_REL, __HIP_MEMORY_SCOPE_AGENT);
        if (a == nb - 1) {
            __hip_atomic_store(cnt, 0, __ATOMIC_RELAXED, __HIP_MEMORY_SCOPE_AGENT);
            __hip_atomic_fetch_add(gen, 1, __ATOMIC_ACQ_REL, __HIP_MEMORY_SCOPE_AGENT);
        } else {
            while (__hip_atomic_load(gen, __ATOMIC_ACQUIRE, __HIP_MEMORY_SCOPE_AGENT) == g)
                __builtin_amdgcn_s_sleep(2);
        }
        __threadfence();    // acquire: invalidate stale lines before next phase
    }
    __syncthreads();
}

// ---------------------------------------------------------------------------
// kbuild: entire CSR build in one launch.
//  P1: per-(bucket,block) histogram + edge-weight max + W^T/c_edge prep
//  P2: parallel exclusive scan of hist[32768] (local scan + block-sum prefix)
//  P3: scatter edges to bucket-partitioned inter via per-block LDS cursors
//  P4: per-bucket CSR finalize (4B records src|bf16(w)<<16) + rowptr
// state[0]=ewmax  state[16]=barrier cnt  state[32]=barrier gen  (memset 0)
__global__ __launch_bounds__(256) void kbuild(
        const int* __restrict__ srcs, const int* __restrict__ dsts,
        const float* __restrict__ ew, int e, int n, int nb, int ep,
        int* __restrict__ hist, int* __restrict__ bsum, int* __restrict__ state,
        int2* __restrict__ inter, unsigned int* __restrict__ edges,
        int* __restrict__ rowptr,
        const float* __restrict__ W0, const float* __restrict__ W1,
        const float* __restrict__ We0, const float* __restrict__ ae0,
        const float* __restrict__ We1, const float* __restrict__ ae1,
        unsigned short* __restrict__ wt0, unsigned short* __restrict__ wt1,
        float* __restrict__ ce) {
    __shared__ int sh[512];
    __shared__ int wsum[4];
    int t = threadIdx.x, blk = blockIdx.x;
    int lane = t & 63, wid = t >> 6;
    int* cnt_ = state + 16;
    int* gen_ = state + 32;

    int tot = e + n;
    int chunk = (tot + NBLK - 1) / NBLK;
    int start = blk * chunk, end = min(start + chunk, tot);

    // ---- P1: histogram + ewmax + param prep
    sh[t] = 0;
    __syncthreads();
    float m = 0.f;
    for (int i = start + t; i < end; i += 256) {
        int d;
        if (i < e) { d = dsts[i]; m = fmaxf(m, ew[i]); }
        else       { d = i - e; }
        atomicAdd(&sh[d >> BSH], 1);
    }
#pragma unroll
    for (int off = 1; off < 64; off <<= 1) m = fmaxf(m, __shfl_xor(m, off));
    if (lane == 0) atomicMax(state, __float_as_int(m));
    {   // W^T prep: exactly one bf16 element per thread across the grid
        int u = blk * 256 + t;               // 0..32767
        const float* W = (u >> 14) ? W1 : W0;
        unsigned short* wt = (u >> 14) ? wt1 : wt0;
        int idx = u & 16383;
        int k = idx >> 7, c = idx & 127;
        wt[c * CN + k] = bf16_of(W[k * CN + c]);
    }
    if (blk == NBLK - 1 && t < 8) {
        const float* We = (t < 4) ? We0 : We1;
        const float* ae = (t < 4) ? ae0 : ae1;
        int h = t & 3;
        float s = 0.f;
        for (int d = 0; d < 32; d++) s += We[h * 32 + d] * ae[h * 32 + d];
        ce[t] = s;
    }
    __syncthreads();
    hist[t * NBLK + blk] = sh[t];
    gbar(cnt_, gen_, NBLK);

    // ---- P2a: block-local exclusive scan of its 256-element linear slice
    {
        int idx = blk * 256 + t;
        int v = hist[idx];
        int s = v;
#pragma unroll
        for (int off = 1; off < 64; off <<= 1) {
            int u = __shfl_up(s, off);
            if (lane >= off) s += u;
        }
        if (lane == 63) wsum[wid] = s;
        __syncthreads();
        int add = 0;
#pragma unroll
        for (int w = 0; w < 4; w++) if (w < wid) add += wsum[w];
        s += add;
        hist[idx] = s - v;
        if (t == 255) bsum[blk] = s;
    }
    gbar(cnt_, gen_, NBLK);

    // ---- P2b: add cross-block prefix (uniform per block -> scalar loads)
    {
        int off2 = 0;
        for (int j = 0; j < blk; j++) off2 += bsum[j];
        hist[blk * 256 + t] += off2;
    }
    gbar(cnt_, gen_, NBLK);

    // ---- P3: scatter to bucket-partitioned inter via LDS cursors
    {
        sh[t] = hist[t * NBLK + blk];
        __syncthreads();
        float wmax = __int_as_float(
            __hip_atomic_load(state, __ATOMIC_RELAXED, __HIP_MEMORY_SCOPE_AGENT));
        for (int i = start + t; i < end; i += 256) {
            int s, d; float w;
            if (i < e) { s = srcs[i]; d = dsts[i]; w = ew[i]; }
            else       { s = i - e;   d = s;       w = wmax;  }
            int p = atomicAdd(&sh[d >> BSH], 1);
            inter[p] = make_int2((d << 16) | s, __float_as_int(w));
        }
    }
    gbar(cnt_, gen_, NBLK);

    // ---- P4: per-bucket CSR finalize (buckets looped over blocks)
    int* cntb = sh;          // [256]
    int* cur  = sh + 256;    // [256]
    for (int b = blk; b < nb; b += NBLK) {
        __syncthreads();
        int rstart = hist[b * NBLK];
        int rend = (b + 1 < 256) ? hist[(b + 1) * NBLK] : ep;
        cntb[t] = 0;
        __syncthreads();
        for (int i = rstart + t; i < rend; i += 256)
            atomicAdd(&cntb[(inter[i].x >> 16) & 255], 1);
        __syncthreads();
        int v = cntb[t];
        int s = v;
#pragma unroll
        for (int off = 1; off < 64; off <<= 1) {
            int u = __shfl_up(s, off);
            if (lane >= off) s += u;
        }
        if (lane == 63) wsum[wid] = s;
        __syncthreads();
        int wexcl = 0;
#pragma unroll
        for (int w = 0; w < 4; w++) if (w < wid) wexcl += wsum[w];
        int excl = wexcl + s - v;
        int node = (b << BSH) + t;
        int gpos = rstart + excl;
        if (node < n) rowptr[node] = gpos;
        if (b == nb - 1 && t == 0) rowptr[n] = ep;
        cur[t] = gpos;
        __syncthreads();
        for (int i = rstart + t; i < rend; i += 256) {
            int2 r = inter[i];
            int p = atomicAdd(&cur[(r.x >> 16) & 255], 1);
            unsigned int wb = bf16_of(__int_as_float(r.y));
            edges[p] = (unsigned int)(r.x & 0xffff) | (wb << 16);
        }
    }
}

// ---------------------------------------------------------------------------
// K4: fused GroupNorm + LeakyReLU(0.01) + MFMA GEMM (bf16 in, fp32 acc)
// + score dots. Block = 64 rows x 128 cols, 256 thr (4 waves).
// inbf16: read node features from packed bf16 (layer 1) vs fp32 (layer 0).
__global__ __launch_bounds__(256, 3) void kgn_gemm7(
        const float* __restrict__ xin, const uint4* __restrict__ xin_b,
        int inbf16, const float* __restrict__ gamma,
        const float* __restrict__ beta, const unsigned short* __restrict__ wt,
        const float* __restrict__ asrc, const float* __restrict__ adst,
        unsigned int* __restrict__ hout, float* __restrict__ ssrc,
        float* __restrict__ sdst, int n) {
    __shared__ short xs[64 * CN];    // 16 KiB
    __shared__ short ws[CN * CN];    // 32 KiB

    int t = threadIdx.x;
    int lane = t & 63, w = t >> 6;
    int m = lane & 15, quad = lane >> 4;
    int block_row = blockIdx.x * 64;

    {
        const uint4* src = (const uint4*)wt;
        uint4* dst = (uint4*)ws;
#pragma unroll
        for (int i = 0; i < 8; i++) {
            int u = t + 256 * i;
            int c = u >> 4, kb = u & 15;
            dst[c * 16 + (kb ^ (c & 15))] = src[u];
        }
    }
    {
        int r = t & 63;
        int row = block_row + r;
        uint4* dst = (uint4*)xs;
#pragma unroll
        for (int u2 = 0; u2 < 2; u2++) {
            int g = (t >> 6) * 2 + u2;       // channel group 0..7 (k=16g..16g+15)
            uint4 lo, hi;
            if (row < n) {
                float v[16];
                if (inbf16) {
                    uint4 A = xin_b[(size_t)row * 16 + g * 2];
                    uint4 B = xin_b[(size_t)row * 16 + g * 2 + 1];
                    unsigned int uu[8] = {A.x,A.y,A.z,A.w,B.x,B.y,B.z,B.w};
#pragma unroll
                    for (int j = 0; j < 8; j++) {
                        v[2*j]   = __uint_as_float(uu[j] << 16);
                        v[2*j+1] = __uint_as_float(uu[j] & 0xffff0000u);
                    }
                } else {
                    const float4* xr = (const float4*)(xin + (size_t)row * CN + g * 16);
                    float4 A = xr[0], B = xr[1], C = xr[2], D = xr[3];
                    float tmp[16] = {A.x,A.y,A.z,A.w,B.x,B.y,B.z,B.w,
                                     C.x,C.y,C.z,C.w,D.x,D.y,D.z,D.w};
#pragma unroll
                    for (int j = 0; j < 16; j++) v[j] = tmp[j];
                }
                float mu = 0.f;
#pragma unroll
                for (int j = 0; j < 16; j++) mu += v[j];
                mu *= 0.0625f;
                float var = 0.f;
#pragma unroll
                for (int j = 0; j < 16; j++) { float d2 = v[j] - mu; var += d2 * d2; }
                var *= 0.0625f;
                float rsv = rsqrtf(var + 1e-5f);
                const float4* gp = (const float4*)(gamma + g * 16);
                const float4* bp = (const float4*)(beta + g * 16);
                float4 g0 = gp[0], g1 = gp[1], g2 = gp[2], g3 = gp[3];
                float4 b0 = bp[0], b1 = bp[1], b2 = bp[2], b3 = bp[3];
                float gv[16] = {g0.x,g0.y,g0.z,g0.w,g1.x,g1.y,g1.z,g1.w,
                                g2.x,g2.y,g2.z,g2.w,g3.x,g3.y,g3.z,g3.w};
                float bv[16] = {b0.x,b0.y,b0.z,b0.w,b1.x,b1.y,b1.z,b1.w,
                                b2.x,b2.y,b2.z,b2.w,b3.x,b3.y,b3.z,b3.w};
                float xn[16];
#pragma unroll
                for (int j = 0; j < 16; j++) {
                    float xv = (v[j] - mu) * rsv * gv[j] + bv[j];
                    xn[j] = xv > 0.f ? xv : 0.01f * xv;
                }
                lo = make_uint4(pack_bf16x2(xn[0], xn[1]),  pack_bf16x2(xn[2], xn[3]),
                                pack_bf16x2(xn[4], xn[5]),  pack_bf16x2(xn[6], xn[7]));
                hi = make_uint4(pack_bf16x2(xn[8], xn[9]),  pack_bf16x2(xn[10], xn[11]),
                                pack_bf16x2(xn[12], xn[13]), pack_bf16x2(xn[14], xn[15]));
            } else {
                lo = make_uint4(0, 0, 0, 0);
                hi = lo;
            }
            dst[r * 16 + ((2 * g)     ^ (r & 15))] = lo;
            dst[r * 16 + ((2 * g + 1) ^ (r & 15))] = hi;
        }
    }
    __syncthreads();

    f32x4 acc[4][2];
#pragma unroll
    for (int i = 0; i < 4; i++) { acc[i][0] = (f32x4)0.f; acc[i][1] = (f32x4)0.f; }

#pragma unroll
    for (int kc = 0; kc < 4; kc++) {
        int kb = 4 * kc + quad;
        bf16x8 af[4], bfr[2];
#pragma unroll
        for (int mt = 0; mt < 4; mt++)
            af[mt] = *(const bf16x8*)&xs[(16 * mt + m) * CN + ((kb ^ m) << 3)];
#pragma unroll
        for (int nt = 0; nt < 2; nt++) {
            int c = 32 * w + 16 * nt + m;        // c&15 == m
            bfr[nt] = *(const bf16x8*)&ws[c * CN + ((kb ^ m) << 3)];
        }
#pragma unroll
        for (int mt = 0; mt < 4; mt++) {
#pragma unroll
            for (int nt = 0; nt < 2; nt++)
                acc[mt][nt] = __builtin_amdgcn_mfma_f32_16x16x32_bf16(
                    af[mt], bfr[nt], acc[mt][nt], 0, 0, 0);
        }
    }

    float asv[2], adv[2];
#pragma unroll
    for (int nt = 0; nt < 2; nt++) {
        asv[nt] = asrc[32 * w + 16 * nt + m];
        adv[nt] = adst[32 * w + 16 * nt + m];
    }
#pragma unroll
    for (int mt = 0; mt < 4; mt++) {
#pragma unroll
        for (int j = 0; j < 4; j++) {
            float p = acc[mt][0][j] * asv[0] + acc[mt][1][j] * asv[1];
            float q = acc[mt][0][j] * adv[0] + acc[mt][1][j] * adv[1];
#pragma unroll
            for (int off = 1; off < 16; off <<= 1) {
                p += __shfl_xor(p, off);
                q += __shfl_xor(q, off);
            }
            if (m == 0) {
                int row = block_row + 16 * mt + 4 * quad + j;
                if (row < n) {
                    ssrc[row * 4 + w] = p;
                    sdst[row * 4 + w] = q;
                }
            }
        }
    }

    __syncthreads();
#pragma unroll
    for (int mt = 0; mt < 4; mt++) {
#pragma unroll
        for (int nt = 0; nt < 2; nt++) {
            int c = 32 * w + 16 * nt + m;
#pragma unroll
            for (int j = 0; j < 4; j++) {
                int rl = 16 * mt + 4 * quad + j;
                xs[rl * CN + c] = (short)bf16_of(acc[mt][nt][j]);
            }
        }
    }
    __syncthreads();
    {
        const uint4* src = (const uint4*)xs;
#pragma unroll
        for (int i = 0; i < 4; i++) {
            int u = t + 256 * i;
            int rl = u >> 4;
            int row = block_row + rl;
            if (row < n)
                *(uint4*)&hout[(size_t)row * 64 + ((u & 15) << 2)] = src[u];
        }
    }
}

// ---------------------------------------------------------------------------
// K6: single-pass softmax aggregation over bf16 h, 4-deep software pipeline.
// 4 B edge records (src | bf16(w)<<16). packout: write packed bf16 (layer 0
// intermediate) vs fp32 (final output).
__global__ __launch_bounds__(256, 8) void kaggr3(
        const uint4* __restrict__ h, const float* __restrict__ ssrc,
        const float* __restrict__ sdst, const int* __restrict__ rowptr,
        const unsigned int* __restrict__ edges, const float* __restrict__ ce4,
        const float* __restrict__ bias, float* __restrict__ out,
        uint4* __restrict__ outb, int packout, int n) {
    int t = threadIdx.x;
    int node = blockIdx.x * 4 + (t >> 6);
    if (node >= n) return;
    int l64 = t & 63;
    int ll = l64 & 15;
    int g  = l64 >> 4;
    int head = ll >> 2;

    int start = rowptr[node], end = rowptr[node + 1];
    float sd = sdst[node * 4 + head];
    float ce = ce4[head];

    float a0=0.f,a1=0.f,a2=0.f,a3=0.f,a4=0.f,a5=0.f,a6=0.f,a7=0.f;
    float se = 0.f;

    int i = start + g;
    for (; i + 12 < end; i += 16) {
        unsigned int er[4];
#pragma unroll
        for (int u = 0; u < 4; u++) er[u] = edges[i + 4 * u];
        float ssv[4]; uint4 U[4];
#pragma unroll
        for (int u = 0; u < 4; u++) {
            int sidx = er[u] & 0xffff;
            ssv[u] = ssrc[sidx * 4 + head];
            U[u] = h[(size_t)sidx * 16 + ll];
        }
#pragma unroll
        for (int u = 0; u < 4; u++) {
            float wv = __uint_as_float(er[u] & 0xffff0000u);
            float l = ssv[u] + sd + wv * ce;
            l = fmaxf(l, 0.2f * l);
            float e = __expf(fminf(l, 80.f));
            float h0 = __uint_as_float(U[u].x << 16);
            float h1 = __uint_as_float(U[u].x & 0xffff0000u);
            float h2 = __uint_as_float(U[u].y << 16);
            float h3 = __uint_as_float(U[u].y & 0xffff0000u);
            float h4 = __uint_as_float(U[u].z << 16);
            float h5 = __uint_as_float(U[u].z & 0xffff0000u);
            float h6 = __uint_as_float(U[u].w << 16);
            float h7 = __uint_as_float(U[u].w & 0xffff0000u);
            se += e;
            a0 = fmaf(e, h0, a0); a1 = fmaf(e, h1, a1);
            a2 = fmaf(e, h2, a2); a3 = fmaf(e, h3, a3);
            a4 = fmaf(e, h4, a4); a5 = fmaf(e, h5, a5);
            a6 = fmaf(e, h6, a6); a7 = fmaf(e, h7, a7);
        }
    }
    for (; i < end; i += 4) {
        unsigned int er = edges[i];
        int sidx = er & 0xffff;
        float ss = ssrc[sidx * 4 + head];
        uint4 U = h[(size_t)sidx * 16 + ll];
        float wv = __uint_as_float(er & 0xffff0000u);
        float l = ss + sd + wv * ce;
        l = fmaxf(l, 0.2f * l);
        float e = __expf(fminf(l, 80.f));
        float h0 = __uint_as_float(U.x << 16);
        float h1 = __uint_as_float(U.x & 0xffff0000u);
        float h2 = __uint_as_float(U.y << 16);
        float h3 = __uint_as_float(U.y & 0xffff0000u);
        float h4 = __uint_as_float(U.z << 16);
        float h5 = __uint_as_float(U.z & 0xffff0000u);
        float h6 = __uint_as_float(U.w << 16);
        float h7 = __uint_as_float(U.w & 0xffff0000u);
        se += e;
        a0 = fmaf(e, h0, a0); a1 = fmaf(e, h1, a1);
        a2 = fmaf(e, h2, a2); a3 = fmaf(e, h3, a3);
        a4 = fmaf(e, h4, a4); a5 = fmaf(e, h5, a5);
        a6 = fmaf(e, h6, a6); a7 = fmaf(e, h7, a7);
    }
#pragma unroll
    for (int off = 16; off < 64; off <<= 1) {
        a0 += __shfl_xor(a0, off); a1 += __shfl_xor(a1, off);
        a2 += __shfl_xor(a2, off); a3 += __shfl_xor(a3, off);
        a4 += __shfl_xor(a4, off); a5 += __shfl_xor(a5, off);
        a6 += __shfl_xor(a6, off); a7 += __shfl_xor(a7, off);
        se += __shfl_xor(se, off);
    }
    if (g == 0) {
        float inv = 1.f / (se + 1e-16f);
        const float4* bp = (const float4*)(bias + ll * 8);
        float4 b0 = bp[0], b1 = bp[1];
        float o0 = a0 * inv + b0.x, o1 = a1 * inv + b0.y;
        float o2 = a2 * inv + b0.z, o3 = a3 * inv + b0.w;
        float o4 = a4 * inv + b1.x, o5 = a5 * inv + b1.y;
        float o6 = a6 * inv + b1.z, o7 = a7 * inv + b1.w;
        if (packout) {
            outb[(size_t)node * 16 + ll] =
                make_uint4(pack_bf16x2(o0, o1), pack_bf16x2(o2, o3),
                           pack_bf16x2(o4, o5), pack_bf16x2(o6, o7));
        } else {
            float4* orow = (float4*)(out + (size_t)node * CN + ll * 8);
            orow[0] = make_float4(o0, o1, o2, o3);
            orow[1] = make_float4(o4, o5, o6, o7);
        }
    }
}

// ---------------------------------------------------------------------------
extern "C" void kernel_launch(void* const* d_in, const int* in_sizes, int n_in,
                              void* d_out, int out_size, void* d_ws, size_t ws_size,
                              hipStream_t stream) {
    const float* x  = (const float*)d_in[0];
    const int*   ei = (const int*)d_in[1];
    const float* ew = (const float*)d_in[2];
    int N_ = in_sizes[0] / CN;
    int E_ = in_sizes[2];
    int EP = E_ + N_;
    int NB = (N_ + 255) >> BSH;

    size_t off = 0;
    auto alloc = [&](size_t bytes) -> void* {
        void* p = (char*)d_ws + off;
        off += (bytes + 255) & ~(size_t)255;
        return p;
    };
    unsigned int* hbuf = (unsigned int*)alloc((size_t)N_ * 64 * 4);  // bf16x2 packed
    uint4* x1b     = (uint4*)alloc((size_t)N_ * 64 * 4);             // bf16 x1
    float* ssrc    = (float*)alloc((size_t)N_ * 4 * 4);
    float* sdst    = (float*)alloc((size_t)N_ * 4 * 4);
    int*   rowptr  = (int*)alloc((size_t)(N_ + 1) * 4);
    unsigned int* edges = (unsigned int*)alloc((size_t)EP * 4);
    int2*  inter   = (int2*)alloc((size_t)EP * 8);
    int*   hist    = (int*)alloc((size_t)256 * NBLK * 4);
    int*   bsum    = (int*)alloc(1024);
    int*   state   = (int*)alloc(256);      // ewmax / barrier cnt / barrier gen
    unsigned short* wt0 = (unsigned short*)alloc((size_t)CN * CN * 2);
    unsigned short* wt1 = (unsigned short*)alloc((size_t)CN * CN * 2);
    float* cedge   = (float*)alloc(256);

    hipMemsetAsync(state, 0, 256, stream);

    const int* srcs = ei;
    const int* dsts = ei + E_;

    kbuild<<<NBLK, 256, 0, stream>>>(
        srcs, dsts, ew, E_, N_, NB, EP, hist, bsum, state, inter, edges, rowptr,
        (const float*)d_in[5], (const float*)d_in[13],
        (const float*)d_in[6], (const float*)d_in[9],
        (const float*)d_in[14], (const float*)d_in[17],
        wt0, wt1, cedge);

    for (int l = 0; l < 2; l++) {
        const float* gamma = (const float*)d_in[3 + l * 8 + 0];
        const float* beta  = (const float*)d_in[3 + l * 8 + 1];
        const float* asrc  = (const float*)d_in[3 + l * 8 + 4];
        const float* adst  = (const float*)d_in[3 + l * 8 + 5];
        const float* bias  = (const float*)d_in[3 + l * 8 + 7];
        const unsigned short* wt = (l == 0) ? wt0 : wt1;

        kgn_gemm7<<<(N_ + 63) / 64, 256, 0, stream>>>(
            x, (const uint4*)x1b, l, gamma, beta, wt, asrc, adst,
            hbuf, ssrc, sdst, N_);
        kaggr3<<<(N_ + 3) / 4, 256, 0, stream>>>(
            (const uint4*)hbuf, ssrc, sdst, rowptr, edges, cedge + l * 4,
            bias, (float*)d_out, x1b, (l == 0) ? 1 : 0, N_);
    }
}

// Round 14
// 268.441 us; speedup vs baseline: 1.2110x; 1.2110x over previous
//
#include <hip/hip_runtime.h>
#include <hip/hip_bf16.h>
#include <math.h>

// N=50000, E=800000, C=128, H=4, D=32, G=8 (group size 16).
#define CN 128
#define NBLK 128         // blocks in bucket-partition phases A/B
#define BSH 8            // bucket = dst >> 8 (256 nodes/bucket); N<2^16 packs in int2

typedef __attribute__((ext_vector_type(8))) short bf16x8;
typedef __attribute__((ext_vector_type(4))) float f32x4;

// fp32 -> bf16 RTNE (bit trick; inputs are finite)
static __device__ inline unsigned int pack_bf16x2(float lo, float hi) {
    unsigned int ul = __float_as_uint(lo);
    unsigned int uh = __float_as_uint(hi);
    ul = (ul + 0x7fffu + ((ul >> 16) & 1u)) >> 16;
    uh = (uh + 0x7fffu + ((uh >> 16) & 1u)) & 0xffff0000u;
    return ul | uh;
}
static __device__ inline unsigned short bf16_of(float v) {
    unsigned int u = __float_as_uint(v);
    return (unsigned short)((u + 0x7fffu + ((u >> 16) & 1u)) >> 16);
}

// ---------------------------------------------------------------------------
// kbA: blocks 0..127: per-(bucket,block) histogram + edge-weight max.
// Block 128/129: transpose W0/W1 (fp32 [k][c] -> bf16 [c][k]).
// Block 130: c_edge[h] for both layers.
__global__ __launch_bounds__(256) void kbA(const int* __restrict__ dsts,
                                           const float* __restrict__ ew,
                                           int e, int n,
                                           int* __restrict__ hist,
                                           int* __restrict__ ewmax,
                                           const float* __restrict__ W0,
                                           const float* __restrict__ W1,
                                           const float* __restrict__ We0,
                                           const float* __restrict__ ae0,
                                           const float* __restrict__ We1,
                                           const float* __restrict__ ae1,
                                           unsigned short* __restrict__ wt0,
                                           unsigned short* __restrict__ wt1,
                                           float* __restrict__ ce) {
    __shared__ int lh[256];
    int t = threadIdx.x, blk = blockIdx.x;
    if (blk >= NBLK) {
        int b = blk - NBLK;
        if (b < 2) {
            const float* W = b ? W1 : W0;
            unsigned short* wt = b ? wt1 : wt0;
            for (int i = t; i < CN * CN; i += 256) {
                int k = i >> 7, c = i & 127;
                wt[c * CN + k] = bf16_of(W[k * CN + c]);
            }
        } else if (t < 8) {
            const float* We = (t < 4) ? We0 : We1;
            const float* ae = (t < 4) ? ae0 : ae1;
            int h = t & 3;
            float s = 0.f;
            for (int d = 0; d < 32; d++) s += We[h * 32 + d] * ae[h * 32 + d];
            ce[t] = s;
        }
        return;
    }
    lh[t] = 0;
    __syncthreads();
    int tot = e + n;
    int chunk = (tot + NBLK - 1) / NBLK;
    int start = blk * chunk, end = min(start + chunk, tot);
    float m = 0.f;
    for (int i = start + t; i < end; i += 256) {
        int d;
        if (i < e) { d = dsts[i]; m = fmaxf(m, ew[i]); }
        else       { d = i - e; }
        atomicAdd(&lh[d >> BSH], 1);
    }
#pragma unroll
    for (int off = 1; off < 64; off <<= 1) m = fmaxf(m, __shfl_xor(m, off));
    if ((t & 63) == 0) atomicMax(ewmax, __float_as_int(m));
    __syncthreads();
    hist[t * NBLK + blk] = lh[t];
}

// kscanL: 128 blocks; block j exclusive-scans hist[256j .. 256j+255] in place,
// writes slice total to bsum[j].
__global__ __launch_bounds__(256) void kscanL(int* __restrict__ a,
                                              int* __restrict__ bsum) {
    __shared__ int wsum[4];
    int t = threadIdx.x, blk = blockIdx.x;
    int idx = blk * 256 + t;
    int v = a[idx];
    int s = v;
    int lane = t & 63, wid = t >> 6;
#pragma unroll
    for (int off = 1; off < 64; off <<= 1) {
        int u = __shfl_up(s, off);
        if (lane >= off) s += u;
    }
    if (lane == 63) wsum[wid] = s;
    __syncthreads();
    int add = 0;
#pragma unroll
    for (int w = 0; w < 4; w++) if (w < wid) add += wsum[w];
    s += add;
    a[idx] = s - v;
    if (t == 255) bsum[blk] = s;
}

// kscanS: one block, exclusive scan of bsum[128] in place.
__global__ __launch_bounds__(128) void kscanS(int* __restrict__ bsum) {
    __shared__ int wtot;
    int t = threadIdx.x;
    int v = bsum[t];
    int s = v;
    int lane = t & 63, wid = t >> 6;
#pragma unroll
    for (int off = 1; off < 64; off <<= 1) {
        int u = __shfl_up(s, off);
        if (lane >= off) s += u;
    }
    if (t == 63) wtot = s;
    __syncthreads();
    if (wid == 1) s += wtot;
    bsum[t] = s - v;
}

// kbB: scatter edges into bucket-partitioned intermediate via per-block LDS
// cursors — each (block,bucket) run is contiguous (full-line HBM writes).
// Cross-block scan offset folded in: hist[u] + bsum[u>>8], u = t*NBLK+blk.
__global__ __launch_bounds__(256) void kbB(const int* __restrict__ srcs,
                                           const int* __restrict__ dsts,
                                           const float* __restrict__ ew,
                                           const int* __restrict__ ewmax,
                                           const int* __restrict__ hsc,
                                           const int* __restrict__ bsum,
                                           int2* __restrict__ inter, int e, int n) {
    __shared__ int cur[256];
    int t = threadIdx.x, blk = blockIdx.x;
    cur[t] = hsc[t * NBLK + blk] + bsum[t >> 1];   // (t*128+blk)>>8 == t>>1
    __syncthreads();
    int tot = e + n;
    float wmax = __int_as_float(*ewmax);
    int chunk = (tot + NBLK - 1) / NBLK;
    int start = blk * chunk, end = min(start + chunk, tot);
    for (int i = start + t; i < end; i += 256) {
        int s, d; float w;
        if (i < e) { s = srcs[i]; d = dsts[i]; w = ew[i]; }
        else       { s = i - e;   d = s;       w = wmax;  }
        int p = atomicAdd(&cur[d >> BSH], 1);
        inter[p] = make_int2((d << 16) | s, __float_as_int(w));
    }
}

// kbC: one block per bucket; builds rowptr + final CSR (4 B records:
// src | bf16(w)<<16) in an L2-local window.
__global__ __launch_bounds__(256) void kbC(const int* __restrict__ hsc,
                                           const int* __restrict__ bsum,
                                           const int2* __restrict__ inter,
                                           unsigned int* __restrict__ edges,
                                           int* __restrict__ rowptr,
                                           int n, int nb, int ep) {
    __shared__ int cnt[256];
    __shared__ int cur[256];
    __shared__ int wsum[4];
    int t = threadIdx.x, b = blockIdx.x;
    int rstart = hsc[b * NBLK] + bsum[b >> 1];
    int rend = (b + 1 < 256) ? (hsc[(b + 1) * NBLK] + bsum[(b + 1) >> 1]) : ep;
    cnt[t] = 0;
    __syncthreads();
    for (int i = rstart + t; i < rend; i += 256)
        atomicAdd(&cnt[(inter[i].x >> 16) & 255], 1);
    __syncthreads();
    int v = cnt[t];
    int s = v;
    int lane = t & 63, wid = t >> 6;
#pragma unroll
    for (int off = 1; off < 64; off <<= 1) {
        int u = __shfl_up(s, off);
        if (lane >= off) s += u;
    }
    if (lane == 63) wsum[wid] = s;
    __syncthreads();
    int wexcl = 0;
#pragma unroll
    for (int w = 0; w < 4; w++) if (w < wid) wexcl += wsum[w];
    int excl = wexcl + s - v;
    int node = (b << BSH) + t;
    int gpos = rstart + excl;
    if (node < n) rowptr[node] = gpos;
    if (b == nb - 1 && t == 0) rowptr[n] = ep;
    cur[t] = gpos;
    __syncthreads();
    for (int i = rstart + t; i < rend; i += 256) {
        int2 r = inter[i];
        int p = atomicAdd(&cur[(r.x >> 16) & 255], 1);
        unsigned int wb = bf16_of(__int_as_float(r.y));
        edges[p] = (unsigned int)(r.x & 0xffff) | (wb << 16);
    }
}

// ---------------------------------------------------------------------------
// K4: fused GroupNorm + LeakyReLU(0.01) + MFMA GEMM (bf16 in, fp32 acc)
// + score dots. Block = 64 rows x 128 cols, 256 thr (4 waves).
// inbf16: read node features from packed bf16 (layer 1) vs fp32 (layer 0).
__global__ __launch_bounds__(256, 3) void kgn_gemm7(
        const float* __restrict__ xin, const uint4* __restrict__ xin_b,
        int inbf16, const float* __restrict__ gamma,
        const float* __restrict__ beta, const unsigned short* __restrict__ wt,
        const float* __restrict__ asrc, const float* __restrict__ adst,
        unsigned int* __restrict__ hout, float* __restrict__ ssrc,
        float* __restrict__ sdst, int n) {
    __shared__ short xs[64 * CN];    // 16 KiB
    __shared__ short ws[CN * CN];    // 32 KiB

    int t = threadIdx.x;
    int lane = t & 63, w = t >> 6;
    int m = lane & 15, quad = lane >> 4;
    int block_row = blockIdx.x * 64;

    {
        const uint4* src = (const uint4*)wt;
        uint4* dst = (uint4*)ws;
#pragma unroll
        for (int i = 0; i < 8; i++) {
            int u = t + 256 * i;
            int c = u >> 4, kb = u & 15;
            dst[c * 16 + (kb ^ (c & 15))] = src[u];
        }
    }
    {
        int r = t & 63;
        int row = block_row + r;
        uint4* dst = (uint4*)xs;
#pragma unroll
        for (int u2 = 0; u2 < 2; u2++) {
            int g = (t >> 6) * 2 + u2;       // channel group 0..7 (k=16g..16g+15)
            uint4 lo, hi;
            if (row < n) {
                float v[16];
                if (inbf16) {
                    uint4 A = xin_b[(size_t)row * 16 + g * 2];
                    uint4 B = xin_b[(size_t)row * 16 + g * 2 + 1];
                    unsigned int uu[8] = {A.x,A.y,A.z,A.w,B.x,B.y,B.z,B.w};
#pragma unroll
                    for (int j = 0; j < 8; j++) {
                        v[2*j]   = __uint_as_float(uu[j] << 16);
                        v[2*j+1] = __uint_as_float(uu[j] & 0xffff0000u);
                    }
                } else {
                    const float4* xr = (const float4*)(xin + (size_t)row * CN + g * 16);
                    float4 A = xr[0], B = xr[1], C = xr[2], D = xr[3];
                    float tmp[16] = {A.x,A.y,A.z,A.w,B.x,B.y,B.z,B.w,
                                     C.x,C.y,C.z,C.w,D.x,D.y,D.z,D.w};
#pragma unroll
                    for (int j = 0; j < 16; j++) v[j] = tmp[j];
                }
                float mu = 0.f;
#pragma unroll
                for (int j = 0; j < 16; j++) mu += v[j];
                mu *= 0.0625f;
                float var = 0.f;
#pragma unroll
                for (int j = 0; j < 16; j++) { float d2 = v[j] - mu; var += d2 * d2; }
                var *= 0.0625f;
                float rsv = rsqrtf(var + 1e-5f);
                const float4* gp = (const float4*)(gamma + g * 16);
                const float4* bp = (const float4*)(beta + g * 16);
                float4 g0 = gp[0], g1 = gp[1], g2 = gp[2], g3 = gp[3];
                float4 b0 = bp[0], b1 = bp[1], b2 = bp[2], b3 = bp[3];
                float gv[16] = {g0.x,g0.y,g0.z,g0.w,g1.x,g1.y,g1.z,g1.w,
                                g2.x,g2.y,g2.z,g2.w,g3.x,g3.y,g3.z,g3.w};
                float bv[16] = {b0.x,b0.y,b0.z,b0.w,b1.x,b1.y,b1.z,b1.w,
                                b2.x,b2.y,b2.z,b2.w,b3.x,b3.y,b3.z,b3.w};
                float xn[16];
#pragma unroll
                for (int j = 0; j < 16; j++) {
                    float xv = (v[j] - mu) * rsv * gv[j] + bv[j];
                    xn[j] = xv > 0.f ? xv : 0.01f * xv;
                }
                lo = make_uint4(pack_bf16x2(xn[0], xn[1]),  pack_bf16x2(xn[2], xn[3]),
                                pack_bf16x2(xn[4], xn[5]),  pack_bf16x2(xn[6], xn[7]));
                hi = make_uint4(pack_bf16x2(xn[8], xn[9]),  pack_bf16x2(xn[10], xn[11]),
                                pack_bf16x2(xn[12], xn[13]), pack_bf16x2(xn[14], xn[15]));
            } else {
                lo = make_uint4(0, 0, 0, 0);
                hi = lo;
            }
            dst[r * 16 + ((2 * g)     ^ (r & 15))] = lo;
            dst[r * 16 + ((2 * g + 1) ^ (r & 15))] = hi;
        }
    }
    __syncthreads();

    f32x4 acc[4][2];
#pragma unroll
    for (int i = 0; i < 4; i++) { acc[i][0] = (f32x4)0.f; acc[i][1] = (f32x4)0.f; }

#pragma unroll
    for (int kc = 0; kc < 4; kc++) {
        int kb = 4 * kc + quad;
        bf16x8 af[4], bfr[2];
#pragma unroll
        for (int mt = 0; mt < 4; mt++)
            af[mt] = *(const bf16x8*)&xs[(16 * mt + m) * CN + ((kb ^ m) << 3)];
#pragma unroll
        for (int nt = 0; nt < 2; nt++) {
            int c = 32 * w + 16 * nt + m;        // c&15 == m
            bfr[nt] = *(const bf16x8*)&ws[c * CN + ((kb ^ m) << 3)];
        }
#pragma unroll
        for (int mt = 0; mt < 4; mt++) {
#pragma unroll
            for (int nt = 0; nt < 2; nt++)
                acc[mt][nt] = __builtin_amdgcn_mfma_f32_16x16x32_bf16(
                    af[mt], bfr[nt], acc[mt][nt], 0, 0, 0);
        }
    }

    float asv[2], adv[2];
#pragma unroll
    for (int nt = 0; nt < 2; nt++) {
        asv[nt] = asrc[32 * w + 16 * nt + m];
        adv[nt] = adst[32 * w + 16 * nt + m];
    }
#pragma unroll
    for (int mt = 0; mt < 4; mt++) {
#pragma unroll
        for (int j = 0; j < 4; j++) {
            float p = acc[mt][0][j] * asv[0] + acc[mt][1][j] * asv[1];
            float q = acc[mt][0][j] * adv[0] + acc[mt][1][j] * adv[1];
#pragma unroll
            for (int off = 1; off < 16; off <<= 1) {
                p += __shfl_xor(p, off);
                q += __shfl_xor(q, off);
            }
            if (m == 0) {
                int row = block_row + 16 * mt + 4 * quad + j;
                if (row < n) {
                    ssrc[row * 4 + w] = p;
                    sdst[row * 4 + w] = q;
                }
            }
        }
    }

    __syncthreads();
#pragma unroll
    for (int mt = 0; mt < 4; mt++) {
#pragma unroll
        for (int nt = 0; nt < 2; nt++) {
            int c = 32 * w + 16 * nt + m;
#pragma unroll
            for (int j = 0; j < 4; j++) {
                int rl = 16 * mt + 4 * quad + j;
                xs[rl * CN + c] = (short)bf16_of(acc[mt][nt][j]);
            }
        }
    }
    __syncthreads();
    {
        const uint4* src = (const uint4*)xs;
#pragma unroll
        for (int i = 0; i < 4; i++) {
            int u = t + 256 * i;
            int rl = u >> 4;
            int row = block_row + rl;
            if (row < n)
                *(uint4*)&hout[(size_t)row * 64 + ((u & 15) << 2)] = src[u];
        }
    }
}

// ---------------------------------------------------------------------------
// K6: single-pass softmax aggregation over bf16 h, 4-deep software pipeline.
// 4 B edge records (src | bf16(w)<<16). packout: write packed bf16 (layer 0
// intermediate) vs fp32 (final output).
__global__ __launch_bounds__(256, 8) void kaggr3(
        const uint4* __restrict__ h, const float* __restrict__ ssrc,
        const float* __restrict__ sdst, const int* __restrict__ rowptr,
        const unsigned int* __restrict__ edges, const float* __restrict__ ce4,
        const float* __restrict__ bias, float* __restrict__ out,
        uint4* __restrict__ outb, int packout, int n) {
    int t = threadIdx.x;
    int node = blockIdx.x * 4 + (t >> 6);
    if (node >= n) return;
    int l64 = t & 63;
    int ll = l64 & 15;
    int g  = l64 >> 4;
    int head = ll >> 2;

    int start = rowptr[node], end = rowptr[node + 1];
    float sd = sdst[node * 4 + head];
    float ce = ce4[head];

    float a0=0.f,a1=0.f,a2=0.f,a3=0.f,a4=0.f,a5=0.f,a6=0.f,a7=0.f;
    float se = 0.f;

    int i = start + g;
    for (; i + 12 < end; i += 16) {
        unsigned int er[4];
#pragma unroll
        for (int u = 0; u < 4; u++) er[u] = edges[i + 4 * u];
        float ssv[4]; uint4 U[4];
#pragma unroll
        for (int u = 0; u < 4; u++) {
            int sidx = er[u] & 0xffff;
            ssv[u] = ssrc[sidx * 4 + head];
            U[u] = h[(size_t)sidx * 16 + ll];
        }
#pragma unroll
        for (int u = 0; u < 4; u++) {
            float wv = __uint_as_float(er[u] & 0xffff0000u);
            float l = ssv[u] + sd + wv * ce;
            l = fmaxf(l, 0.2f * l);
            float e = __expf(fminf(l, 80.f));
            float h0 = __uint_as_float(U[u].x << 16);
            float h1 = __uint_as_float(U[u].x & 0xffff0000u);
            float h2 = __uint_as_float(U[u].y << 16);
            float h3 = __uint_as_float(U[u].y & 0xffff0000u);
            float h4 = __uint_as_float(U[u].z << 16);
            float h5 = __uint_as_float(U[u].z & 0xffff0000u);
            float h6 = __uint_as_float(U[u].w << 16);
            float h7 = __uint_as_float(U[u].w & 0xffff0000u);
            se += e;
            a0 = fmaf(e, h0, a0); a1 = fmaf(e, h1, a1);
            a2 = fmaf(e, h2, a2); a3 = fmaf(e, h3, a3);
            a4 = fmaf(e, h4, a4); a5 = fmaf(e, h5, a5);
            a6 = fmaf(e, h6, a6); a7 = fmaf(e, h7, a7);
        }
    }
    for (; i < end; i += 4) {
        unsigned int er = edges[i];
        int sidx = er & 0xffff;
        float ss = ssrc[sidx * 4 + head];
        uint4 U = h[(size_t)sidx * 16 + ll];
        float wv = __uint_as_float(er & 0xffff0000u);
        float l = ss + sd + wv * ce;
        l = fmaxf(l, 0.2f * l);
        float e = __expf(fminf(l, 80.f));
        float h0 = __uint_as_float(U.x << 16);
        float h1 = __uint_as_float(U.x & 0xffff0000u);
        float h2 = __uint_as_float(U.y << 16);
        float h3 = __uint_as_float(U.y & 0xffff0000u);
        float h4 = __uint_as_float(U.z << 16);
        float h5 = __uint_as_float(U.z & 0xffff0000u);
        float h6 = __uint_as_float(U.w << 16);
        float h7 = __uint_as_float(U.w & 0xffff0000u);
        se += e;
        a0 = fmaf(e, h0, a0); a1 = fmaf(e, h1, a1);
        a2 = fmaf(e, h2, a2); a3 = fmaf(e, h3, a3);
        a4 = fmaf(e, h4, a4); a5 = fmaf(e, h5, a5);
        a6 = fmaf(e, h6, a6); a7 = fmaf(e, h7, a7);
    }
#pragma unroll
    for (int off = 16; off < 64; off <<= 1) {
        a0 += __shfl_xor(a0, off); a1 += __shfl_xor(a1, off);
        a2 += __shfl_xor(a2, off); a3 += __shfl_xor(a3, off);
        a4 += __shfl_xor(a4, off); a5 += __shfl_xor(a5, off);
        a6 += __shfl_xor(a6, off); a7 += __shfl_xor(a7, off);
        se += __shfl_xor(se, off);
    }
    if (g == 0) {
        float inv = 1.f / (se + 1e-16f);
        const float4* bp = (const float4*)(bias + ll * 8);
        float4 b0 = bp[0], b1 = bp[1];
        float o0 = a0 * inv + b0.x, o1 = a1 * inv + b0.y;
        float o2 = a2 * inv + b0.z, o3 = a3 * inv + b0.w;
        float o4 = a4 * inv + b1.x, o5 = a5 * inv + b1.y;
        float o6 = a6 * inv + b1.z, o7 = a7 * inv + b1.w;
        if (packout) {
            outb[(size_t)node * 16 + ll] =
                make_uint4(pack_bf16x2(o0, o1), pack_bf16x2(o2, o3),
                           pack_bf16x2(o4, o5), pack_bf16x2(o6, o7));
        } else {
            float4* orow = (float4*)(out + (size_t)node * CN + ll * 8);
            orow[0] = make_float4(o0, o1, o2, o3);
            orow[1] = make_float4(o4, o5, o6, o7);
        }
    }
}

// ---------------------------------------------------------------------------
extern "C" void kernel_launch(void* const* d_in, const int* in_sizes, int n_in,
                              void* d_out, int out_size, void* d_ws, size_t ws_size,
                              hipStream_t stream) {
    const float* x  = (const float*)d_in[0];
    const int*   ei = (const int*)d_in[1];
    const float* ew = (const float*)d_in[2];
    int N_ = in_sizes[0] / CN;
    int E_ = in_sizes[2];
    int EP = E_ + N_;
    int NB = (N_ + 255) >> BSH;

    size_t off = 0;
    auto alloc = [&](size_t bytes) -> void* {
        void* p = (char*)d_ws + off;
        off += (bytes + 255) & ~(size_t)255;
        return p;
    };
    unsigned int* hbuf = (unsigned int*)alloc((size_t)N_ * 64 * 4);  // bf16x2 packed
    uint4* x1b     = (uint4*)alloc((size_t)N_ * 64 * 4);             // bf16 x1
    float* ssrc    = (float*)alloc((size_t)N_ * 4 * 4);
    float* sdst    = (float*)alloc((size_t)N_ * 4 * 4);
    int*   rowptr  = (int*)alloc((size_t)(N_ + 1) * 4);
    unsigned int* edges = (unsigned int*)alloc((size_t)EP * 4);
    int2*  inter   = (int2*)alloc((size_t)EP * 8);
    int*   hist    = (int*)alloc((size_t)256 * NBLK * 4);
    int*   bsum    = (int*)alloc(1024);
    int*   ewmax   = (int*)alloc(256);
    unsigned short* wt0 = (unsigned short*)alloc((size_t)CN * CN * 2);
    unsigned short* wt1 = (unsigned short*)alloc((size_t)CN * CN * 2);
    float* cedge   = (float*)alloc(256);

    hipMemsetAsync(ewmax, 0, 4, stream);

    const int* srcs = ei;
    const int* dsts = ei + E_;

    kbA<<<NBLK + 3, 256, 0, stream>>>(dsts, ew, E_, N_, hist, ewmax,
                                      (const float*)d_in[5], (const float*)d_in[13],
                                      (const float*)d_in[6], (const float*)d_in[9],
                                      (const float*)d_in[14], (const float*)d_in[17],
                                      wt0, wt1, cedge);
    kscanL<<<NBLK, 256, 0, stream>>>(hist, bsum);
    kscanS<<<1, 128, 0, stream>>>(bsum);
    kbB<<<NBLK, 256, 0, stream>>>(srcs, dsts, ew, ewmax, hist, bsum, inter, E_, N_);
    kbC<<<NB, 256, 0, stream>>>(hist, bsum, inter, edges, rowptr, N_, NB, EP);

    for (int l = 0; l < 2; l++) {
        const float* gamma = (const float*)d_in[3 + l * 8 + 0];
        const float* beta  = (const float*)d_in[3 + l * 8 + 1];
        const float* asrc  = (const float*)d_in[3 + l * 8 + 4];
        const float* adst  = (const float*)d_in[3 + l * 8 + 5];
        const float* bias  = (const float*)d_in[3 + l * 8 + 7];
        const unsigned short* wt = (l == 0) ? wt0 : wt1;

        kgn_gemm7<<<(N_ + 63) / 64, 256, 0, stream>>>(
            x, (const uint4*)x1b, l, gamma, beta, wt, asrc, adst,
            hbuf, ssrc, sdst, N_);
        kaggr3<<<(N_ + 3) / 4, 256, 0, stream>>>(
            (const uint4*)hbuf, ssrc, sdst, rowptr, edges, cedge + l * 4,
            bias, (float*)d_out, x1b, (l == 0) ? 1 : 0, N_);
    }
}